// Round 1
// baseline (149.742 us; speedup 1.0000x reference)
//
#include <hip/hip_runtime.h>

typedef __bf16 bf16;
typedef __attribute__((ext_vector_type(8))) __bf16 bf16x8;
typedef __attribute__((ext_vector_type(4))) __bf16 bf16x4;
typedef __attribute__((ext_vector_type(4))) float f32x4;

#define LDP 72  // 64 + 8 pad (row stride 144B = 16B-aligned, ~2-way LDS conflicts)

// ---------------- problem constants ----------------
static constexpr int ROWS = 16384;   // BS*N_AGENTS
static constexpr int HID  = 256;

// ---------------- workspace layout (bf16 elements) ----------------
static constexpr size_t OFF_INBF = 0;            // [16384,128]
static constexpr size_t OFF_MSG  = 2097152;      // [16384,256]
static constexpr size_t OFF_XH   = 6291456;      // [16384,512]  X | H
static constexpr size_t OFF_WCAT = 14680064;     // [512,512]    Wih_rz | Whh_rz
static constexpr size_t OFF_WNI  = 14942208;     // [256,256]    Wih n-gate
static constexpr size_t OFF_WNH  = 15007744;     // [256,256]    Whh n-gate
static constexpr size_t OFF_FC1W = 15073280;     // [256,128]
static constexpr size_t OFF_QW   = 15106048;     // [64,256]
static constexpr size_t OFF_KW   = 15122432;     // [64,256]
static constexpr size_t OFF_VW   = 15138816;     // [256,256]
static constexpr size_t OFF_F2AW = 15204352;     // [256,512]
static constexpr size_t OFF_F2BW = 15335424;     // [16,256]
static constexpr size_t OFF_RZ   = 15339520;     // [16384,512]  r | z (sigmoid applied)
static constexpr size_t OFF_HM   = 23728128;     // [16384,512]  h | m_agg
static constexpr size_t OFF_QB   = 32116736;     // [16384,64]
static constexpr size_t OFF_MSGK = 33165312;     // [16384,64]
static constexpr size_t OFF_MSGV = 34213888;     // [16384,256]
static constexpr size_t OFF_YBF  = 38408192;     // [16384,256]

// ---------------- f32 -> bf16 conversion (with strided scatter for concats) ----------------
struct CvtSeg { const float* src; bf16* dst; int n; int cw; int ld; int off; };
struct CvtArgs { CvtSeg seg[14]; int count; };

__global__ __launch_bounds__(256) void convert_k(CvtArgs a) {
    const int tid = blockIdx.x * blockDim.x + threadIdx.x;
    const int stride = gridDim.x * blockDim.x;
    for (int s = 0; s < a.count; ++s) {
        const float* __restrict__ src = a.seg[s].src;
        bf16* __restrict__ dst = a.seg[s].dst;
        const int n4 = a.seg[s].n >> 2;
        const int cw = a.seg[s].cw, ld = a.seg[s].ld, off = a.seg[s].off;
        for (int i = tid; i < n4; i += stride) {
            float4 f = *(const float4*)(src + (size_t)i * 4);
            int e = i * 4;
            int d = (e / cw) * ld + off + (e % cw);
            bf16x4 o = { (bf16)f.x, (bf16)f.y, (bf16)f.z, (bf16)f.w };
            *(bf16x4*)(dst + d) = o;
        }
    }
}

// ---------------- generic GEMM: C = act(A @ W^T + bias [+bias2]) ----------------
// A: [M,K] bf16 row-major (leading dim lda); W: [N,K] bf16 (leading dim ldw).
// ACT: 0=none 1=relu 2=sigmoid. Optional bf16 and/or f32 outputs with own ld.
template<int BM, int BN, int WAVES_M, int WAVES_N, int ACT>
__global__ __launch_bounds__(WAVES_M*WAVES_N*64)
void gemm_bt(const bf16* __restrict__ A, int lda,
             const bf16* __restrict__ W, int ldw,
             const float* __restrict__ bias, const float* __restrict__ bias2,
             bf16* __restrict__ outB, int ldob,
             float* __restrict__ outF, int ldof,
             int K)
{
    constexpr int NT = WAVES_M * WAVES_N * 64;
    constexpr int WM = BM / WAVES_M, WN = BN / WAVES_N;
    constexpr int FM = WM / 16, FN = WN / 16;
    __shared__ bf16 sA[BM * LDP];
    __shared__ bf16 sW[BN * LDP];
    const int tid = threadIdx.x;
    const int wave = tid >> 6, lane = tid & 63;
    const int wm = wave / WAVES_N, wn = wave % WAVES_N;
    const int m0 = blockIdx.x * BM;
    const int n0 = blockIdx.y * BN;

    f32x4 acc[FM][FN] = {};

    for (int k0 = 0; k0 < K; k0 += 64) {
        for (int c = tid; c < BM * 8; c += NT) {
            int r = c >> 3, ch = c & 7;
            *(uint4*)&sA[r * LDP + ch * 8] =
                *(const uint4*)(A + (size_t)(m0 + r) * lda + k0 + ch * 8);
        }
        for (int c = tid; c < BN * 8; c += NT) {
            int r = c >> 3, ch = c & 7;
            *(uint4*)&sW[r * LDP + ch * 8] =
                *(const uint4*)(W + (size_t)(n0 + r) * ldw + k0 + ch * 8);
        }
        __syncthreads();
        #pragma unroll
        for (int kk = 0; kk < 64; kk += 32) {
            const int ko = kk + (lane >> 4) * 8;
            bf16x8 af[FM], bfr[FN];
            #pragma unroll
            for (int i = 0; i < FM; ++i)
                af[i] = *(const bf16x8*)&sA[(wm * WM + i * 16 + (lane & 15)) * LDP + ko];
            #pragma unroll
            for (int j = 0; j < FN; ++j)
                bfr[j] = *(const bf16x8*)&sW[(wn * WN + j * 16 + (lane & 15)) * LDP + ko];
            #pragma unroll
            for (int i = 0; i < FM; ++i)
                #pragma unroll
                for (int j = 0; j < FN; ++j)
                    acc[i][j] = __builtin_amdgcn_mfma_f32_16x16x32_bf16(af[i], bfr[j], acc[i][j], 0, 0, 0);
        }
        __syncthreads();
    }

    #pragma unroll
    for (int i = 0; i < FM; ++i) {
        #pragma unroll
        for (int j = 0; j < FN; ++j) {
            const int col = n0 + wn * WN + j * 16 + (lane & 15);
            const int rbase = m0 + wm * WM + i * 16 + ((lane >> 4) << 2);
            float bv = 0.f;
            if (bias)  bv += bias[col];
            if (bias2) bv += bias2[col];
            #pragma unroll
            for (int r = 0; r < 4; ++r) {
                float v = acc[i][j][r] + bv;
                if (ACT == 1) v = fmaxf(v, 0.f);
                else if (ACT == 2) v = 1.f / (1.f + __expf(-v));
                const int row = rbase + r;
                if (outF) outF[(size_t)row * ldof + col] = v;
                if (outB) outB[(size_t)row * ldob + col] = (bf16)v;
            }
        }
    }
}

// ---------------- GRU phase B: i_n = X@Wni^T, h_n = H@Wnh^T, full gate epilogue ----------------
// BM=64, BN=64, 4 waves (2x2), K=256. X = XH[:,0:256], H = XH[:,256:512].
__global__ __launch_bounds__(256)
void gru_b_k(const bf16* __restrict__ XH,
             const bf16* __restrict__ Wni, const bf16* __restrict__ Wnh,
             const float* __restrict__ b_in, const float* __restrict__ b_hn, // already +512
             const bf16* __restrict__ rz, const float* __restrict__ hidden,
             float* __restrict__ h_out, bf16* __restrict__ HM)
{
    __shared__ bf16 sX[64 * LDP];
    __shared__ bf16 sH[64 * LDP];
    __shared__ bf16 sWi[64 * LDP];
    __shared__ bf16 sWh[64 * LDP];
    const int tid = threadIdx.x;
    const int wave = tid >> 6, lane = tid & 63;
    const int wm = wave >> 1, wn = wave & 1;
    const int m0 = blockIdx.x * 64;
    const int n0 = blockIdx.y * 64;

    f32x4 ai[2][2] = {};
    f32x4 ah[2][2] = {};

    for (int k0 = 0; k0 < 256; k0 += 64) {
        for (int c = tid; c < 512; c += 256) {
            int r = c >> 3, ch = c & 7;
            *(uint4*)&sX[r * LDP + ch * 8]  = *(const uint4*)(XH + (size_t)(m0 + r) * 512 + k0 + ch * 8);
            *(uint4*)&sH[r * LDP + ch * 8]  = *(const uint4*)(XH + (size_t)(m0 + r) * 512 + 256 + k0 + ch * 8);
            *(uint4*)&sWi[r * LDP + ch * 8] = *(const uint4*)(Wni + (size_t)(n0 + r) * 256 + k0 + ch * 8);
            *(uint4*)&sWh[r * LDP + ch * 8] = *(const uint4*)(Wnh + (size_t)(n0 + r) * 256 + k0 + ch * 8);
        }
        __syncthreads();
        #pragma unroll
        for (int kk = 0; kk < 64; kk += 32) {
            const int ko = kk + (lane >> 4) * 8;
            bf16x8 ax[2], axh[2], bi[2], bh[2];
            #pragma unroll
            for (int i = 0; i < 2; ++i) {
                ax[i]  = *(const bf16x8*)&sX[(wm * 32 + i * 16 + (lane & 15)) * LDP + ko];
                axh[i] = *(const bf16x8*)&sH[(wm * 32 + i * 16 + (lane & 15)) * LDP + ko];
                bi[i]  = *(const bf16x8*)&sWi[(wn * 32 + i * 16 + (lane & 15)) * LDP + ko];
                bh[i]  = *(const bf16x8*)&sWh[(wn * 32 + i * 16 + (lane & 15)) * LDP + ko];
            }
            #pragma unroll
            for (int i = 0; i < 2; ++i)
                #pragma unroll
                for (int j = 0; j < 2; ++j) {
                    ai[i][j] = __builtin_amdgcn_mfma_f32_16x16x32_bf16(ax[i], bi[j], ai[i][j], 0, 0, 0);
                    ah[i][j] = __builtin_amdgcn_mfma_f32_16x16x32_bf16(axh[i], bh[j], ah[i][j], 0, 0, 0);
                }
        }
        __syncthreads();
    }

    #pragma unroll
    for (int i = 0; i < 2; ++i) {
        #pragma unroll
        for (int j = 0; j < 2; ++j) {
            const int col = n0 + wn * 32 + j * 16 + (lane & 15);
            const int rbase = m0 + wm * 32 + i * 16 + ((lane >> 4) << 2);
            const float bi_v = b_in[col], bh_v = b_hn[col];
            #pragma unroll
            for (int r = 0; r < 4; ++r) {
                const int row = rbase + r;
                float i_n = ai[i][j][r] + bi_v;
                float h_n = ah[i][j][r] + bh_v;
                float rr = (float)rz[(size_t)row * 512 + col];
                float zz = (float)rz[(size_t)row * 512 + 256 + col];
                float nn = tanhf(i_n + rr * h_n);
                float hd = hidden[(size_t)row * 256 + col];
                float h = (1.f - zz) * nn + zz * hd;
                h_out[(size_t)row * 256 + col] = h;
                HM[(size_t)row * 512 + col] = (bf16)h;
            }
        }
    }
}

// ---------------- attention: gather top-k, logits, softmax, weighted V aggregate ----------------
__global__ __launch_bounds__(256)
void attn_k(const bf16* __restrict__ qb, const bf16* __restrict__ kb,
            const bf16* __restrict__ vb, const int* __restrict__ topk,
            const float* __restrict__ v_bias,
            float* __restrict__ magg_out, bf16* __restrict__ HM)
{
    const int unit = blockIdx.x * 4 + (threadIdx.x >> 6);   // (b,n) flat
    const int lane = threadIdx.x & 63;
    const int b = unit >> 6;
    const float qv = (float)qb[(size_t)unit * 64 + lane];
    const int* idx = topk + (size_t)unit * 8;

    int rows[8];
    float logit[8];
    #pragma unroll
    for (int k = 0; k < 8; ++k) {
        rows[k] = (b << 6) + idx[k];
        float s = qv * (float)kb[(size_t)rows[k] * 64 + lane];
        #pragma unroll
        for (int off = 32; off; off >>= 1) s += __shfl_xor(s, off);
        logit[k] = s * 0.125f;  // 1/sqrt(64)
    }
    float mx = logit[0];
    #pragma unroll
    for (int k = 1; k < 8; ++k) mx = fmaxf(mx, logit[k]);
    float e[8], den = 0.f;
    #pragma unroll
    for (int k = 0; k < 8; ++k) { e[k] = __expf(logit[k] - mx); den += e[k]; }
    const float inv = 1.f / den;

    const int d0 = lane * 4;
    float a0 = 0.f, a1 = 0.f, a2 = 0.f, a3 = 0.f;
    #pragma unroll
    for (int k = 0; k < 8; ++k) {
        const float w = e[k] * inv;
        bf16x4 v = *(const bf16x4*)(vb + (size_t)rows[k] * 256 + d0);
        a0 += w * (float)v[0]; a1 += w * (float)v[1];
        a2 += w * (float)v[2]; a3 += w * (float)v[3];
    }
    a0 += v_bias[d0]; a1 += v_bias[d0 + 1]; a2 += v_bias[d0 + 2]; a3 += v_bias[d0 + 3];
    float4 res = { a0, a1, a2, a3 };
    *(float4*)(magg_out + (size_t)unit * 256 + d0) = res;
    bf16x4 rb = { (bf16)a0, (bf16)a1, (bf16)a2, (bf16)a3 };
    *(bf16x4*)(HM + (size_t)unit * 512 + 256 + d0) = rb;
}

// ---------------- launch ----------------
extern "C" void kernel_launch(void* const* d_in, const int* in_sizes, int n_in,
                              void* d_out, int out_size, void* d_ws, size_t ws_size,
                              hipStream_t stream)
{
    const float* in_f    = (const float*)d_in[0];
    const float* hid_f   = (const float*)d_in[1];
    const float* msg_f   = (const float*)d_in[2];
    const int*   topk    = (const int*)d_in[3];
    const float* fc1w_f  = (const float*)d_in[4];
    const float* fc1_b   = (const float*)d_in[5];
    const float* wih_f   = (const float*)d_in[6];
    const float* b_ih    = (const float*)d_in[7];
    const float* whh_f   = (const float*)d_in[8];
    const float* b_hh    = (const float*)d_in[9];
    const float* qw_f    = (const float*)d_in[10];
    const float* q_b     = (const float*)d_in[11];
    const float* kw_f    = (const float*)d_in[12];
    // d_in[13] = k_b: softmax-invariant, dropped.
    const float* vw_f    = (const float*)d_in[14];
    const float* v_b     = (const float*)d_in[15];
    const float* f2aw_f  = (const float*)d_in[16];
    const float* f2a_b   = (const float*)d_in[17];
    const float* f2bw_f  = (const float*)d_in[18];
    const float* f2b_b   = (const float*)d_in[19];

    bf16* ws = (bf16*)d_ws;
    bf16* in_bf  = ws + OFF_INBF;
    bf16* msg_bf = ws + OFF_MSG;
    bf16* XH     = ws + OFF_XH;
    bf16* Wcat   = ws + OFF_WCAT;
    bf16* Wni    = ws + OFF_WNI;
    bf16* Wnh    = ws + OFF_WNH;
    bf16* fc1w   = ws + OFF_FC1W;
    bf16* qw     = ws + OFF_QW;
    bf16* kw     = ws + OFF_KW;
    bf16* vw     = ws + OFF_VW;
    bf16* f2aw   = ws + OFF_F2AW;
    bf16* f2bw   = ws + OFF_F2BW;
    bf16* rz     = ws + OFF_RZ;
    bf16* HM     = ws + OFF_HM;
    bf16* qbf    = ws + OFF_QB;
    bf16* msgk   = ws + OFF_MSGK;
    bf16* msgv   = ws + OFF_MSGV;
    bf16* ybf    = ws + OFF_YBF;

    float* q_out    = (float*)d_out;                    // [16384,16]
    float* h_out    = q_out + (size_t)ROWS * 16;        // [16384,256]
    float* magg_out = h_out + (size_t)ROWS * HID;       // [16384,256]

    // 1) convert everything to bf16 (with concat scatters for XH / Wcat)
    CvtArgs ca{};
    int s = 0;
    auto add = [&](const float* src, bf16* dst, int n, int cw, int ld, int off) {
        ca.seg[s].src = src; ca.seg[s].dst = dst; ca.seg[s].n = n;
        ca.seg[s].cw = cw; ca.seg[s].ld = ld; ca.seg[s].off = off; ++s;
    };
    add(in_f,   in_bf, 2097152, 2097152, 0, 0);
    add(hid_f,  XH,    4194304, 256, 512, 256);      // hidden -> XH[:,256:512]
    add(msg_f,  msg_bf,4194304, 4194304, 0, 0);
    add(fc1w_f, fc1w,  32768,   32768, 0, 0);
    add(wih_f,  Wcat,  131072,  256, 512, 0);        // Wih rows 0..511 -> Wcat[:,0:256]
    add(whh_f,  Wcat,  131072,  256, 512, 256);      // Whh rows 0..511 -> Wcat[:,256:512]
    add(wih_f + 131072, Wni, 65536, 65536, 0, 0);    // n-gate rows 512..767
    add(whh_f + 131072, Wnh, 65536, 65536, 0, 0);
    add(qw_f,   qw,    16384,  16384, 0, 0);
    add(kw_f,   kw,    16384,  16384, 0, 0);
    add(vw_f,   vw,    65536,  65536, 0, 0);
    add(f2aw_f, f2aw,  131072, 131072, 0, 0);
    add(f2bw_f, f2bw,  4096,   4096, 0, 0);
    ca.count = s;
    convert_k<<<1024, 256, 0, stream>>>(ca);

    // 2) fc1: X = relu(in @ fc1_w^T + b) -> XH[:,0:256]
    gemm_bt<128, 64, 2, 2, 1><<<dim3(128, 4), 256, 0, stream>>>(
        in_bf, 128, fc1w, 128, fc1_b, nullptr, XH, 512, nullptr, 0, 128);

    // 3) GRU-A: rz = sigmoid([X|H] @ Wcat^T + b_ih[0:512] + b_hh[0:512])
    gemm_bt<128, 64, 2, 2, 2><<<dim3(128, 8), 256, 0, stream>>>(
        XH, 512, Wcat, 512, b_ih, b_hh, rz, 512, nullptr, 0, 512);

    // 4) msg_k = msg @ k_w^T  (k_b dropped: softmax-invariant)
    gemm_bt<64, 64, 2, 2, 0><<<dim3(256, 1), 256, 0, stream>>>(
        msg_bf, 256, kw, 256, nullptr, nullptr, msgk, 64, nullptr, 0, 256);

    // 5) msg_v = msg @ v_w^T  (v_b added post-aggregation)
    gemm_bt<128, 64, 2, 2, 0><<<dim3(128, 4), 256, 0, stream>>>(
        msg_bf, 256, vw, 256, nullptr, nullptr, msgv, 256, nullptr, 0, 256);

    // 6) GRU-B: h -> d_out h-section + HM[:,0:256]
    gru_b_k<<<dim3(256, 4), 256, 0, stream>>>(
        XH, Wni, Wnh, b_ih + 512, b_hh + 512, rz, hid_f, h_out, HM);

    // 7) q = h @ q_w^T + q_b
    gemm_bt<64, 64, 2, 2, 0><<<dim3(256, 1), 256, 0, stream>>>(
        HM, 512, qw, 256, q_b, nullptr, qbf, 64, nullptr, 0, 256);

    // 8) attention gather + softmax + aggregate -> d_out magg + HM[:,256:512]
    attn_k<<<4096, 256, 0, stream>>>(qbf, msgk, msgv, topk, v_b, magg_out, HM);

    // 9) fc2a: y = relu([h|m_agg] @ fc2a_w^T + b)
    gemm_bt<128, 64, 2, 2, 1><<<dim3(128, 4), 256, 0, stream>>>(
        HM, 512, f2aw, 512, f2a_b, nullptr, ybf, 256, nullptr, 0, 512);

    // 10) fc2b: q_out = y @ fc2b_w^T + b -> d_out[0:16384*16] (f32)
    gemm_bt<128, 16, 4, 1, 0><<<dim3(128, 1), 256, 0, stream>>>(
        ybf, 256, f2bw, 256, f2b_b, nullptr, nullptr, 0, q_out, 16, 256);
}

// Round 2
// 129.101 us; speedup vs baseline: 1.1599x; 1.1599x over previous
//
#include <hip/hip_runtime.h>

typedef __bf16 bf16;
typedef __attribute__((ext_vector_type(8))) __bf16 bf16x8;
typedef __attribute__((ext_vector_type(4))) __bf16 bf16x4;
typedef __attribute__((ext_vector_type(4))) float f32x4;

static constexpr int ROWS = 16384;   // BS*N_AGENTS

// ---------------- workspace layout (bf16 elements) ----------------
static constexpr size_t OFF_WR   = 0;         // Wr_cat  [256,512]
static constexpr size_t OFF_WZ   = 131072;    // Wz_cat  [256,512]
static constexpr size_t OFF_WNI  = 262144;    // Wni     [256,256]
static constexpr size_t OFF_WNH  = 327680;    // Wnh     [256,256]
static constexpr size_t OFF_FC1W = 393216;    // fc1w    [256,128]
static constexpr size_t OFF_QW   = 425984;    // qw      [64,256]
static constexpr size_t OFF_WKV  = 442368;    // Wkv     [320,256] (kw rows 0..63, vw rows 64..319)
static constexpr size_t OFF_F2AW = 524288;    // f2aw    [256,512]
static constexpr size_t OFF_F2BW = 655360;    // f2bw    [16,256]
static constexpr size_t OFF_QB   = 659456;    // qbf     [16384,64]
static constexpr size_t OFF_MSGK = 1708032;   // msgk    [16384,64]
static constexpr size_t OFF_MSGV = 2756608;   // msgv    [16384,256]

// ---------------- weight convert (f32 -> bf16, with strided scatter for concats) ----------------
struct CvtSeg { const float* src; bf16* dst; int n; int cw; int ld; int off; };
struct CvtArgs { CvtSeg seg[14]; int count; };

__global__ __launch_bounds__(256) void convert_k(CvtArgs a) {
    const int tid = blockIdx.x * blockDim.x + threadIdx.x;
    const int stride = gridDim.x * blockDim.x;
    for (int s = 0; s < a.count; ++s) {
        const float* __restrict__ src = a.seg[s].src;
        bf16* __restrict__ dst = a.seg[s].dst;
        const int n4 = a.seg[s].n >> 2;
        const int cw = a.seg[s].cw, ld = a.seg[s].ld, off = a.seg[s].off;
        for (int i = tid; i < n4; i += stride) {
            float4 f = *(const float4*)(src + (size_t)i * 4);
            int e = i * 4;
            int d = a.seg[s].ld ? (e / cw) * ld + off + (e % cw) : e;
            bf16x4 o = { (bf16)f.x, (bf16)f.y, (bf16)f.z, (bf16)f.w };
            *(bf16x4*)(dst + d) = o;
        }
    }
}

// ---------------- MFMA helper: acc += A_lds @ W_global^T over KTILE ----------------
template<int FM, int FN, int KTILE>
__device__ __forceinline__ void mm_f(f32x4 (&acc)[FM][FN],
    const bf16* __restrict__ sA, int lda,
    const bf16* __restrict__ W, int ldw, int lane)
{
    const int lr = lane & 15, lk = (lane >> 4) << 3;
    #pragma unroll
    for (int k0 = 0; k0 < KTILE; k0 += 32) {
        bf16x8 a[FM], b[FN];
        #pragma unroll
        for (int i = 0; i < FM; ++i)
            a[i] = *(const bf16x8*)&sA[(i * 16 + lr) * lda + k0 + lk];
        #pragma unroll
        for (int j = 0; j < FN; ++j)
            b[j] = *(const bf16x8*)(W + (size_t)(j * 16 + lr) * ldw + k0 + lk);
        #pragma unroll
        for (int i = 0; i < FM; ++i)
            #pragma unroll
            for (int j = 0; j < FN; ++j)
                acc[i][j] = __builtin_amdgcn_mfma_f32_16x16x32_bf16(a[i], b[j], acc[i][j], 0, 0, 0);
    }
}

__device__ __forceinline__ float sigmf(float x) { return 1.f / (1.f + __expf(-x)); }
__device__ __forceinline__ float tanh_fast(float x) {
    x = fminf(fmaxf(x, -15.f), 15.f);
    float e2 = __expf(2.f * x);
    return (e2 - 1.f) / (e2 + 1.f);
}

// ---------------- GRU megakernel: fc1 + GRU gates + h + q projection ----------------
// 256 blocks x 512 threads; BM=64 rows/block; wave grid 2x4.
__global__ __launch_bounds__(512, 1)
void gru_mega_k(const float* __restrict__ in_f, const float* __restrict__ hid_f,
                const bf16* __restrict__ Wfc1, const float* __restrict__ fc1_b,
                const bf16* __restrict__ Wr, const bf16* __restrict__ Wz,
                const bf16* __restrict__ Wni, const bf16* __restrict__ Wnh,
                const float* __restrict__ b_ih, const float* __restrict__ b_hh,
                const bf16* __restrict__ Wq, const float* __restrict__ q_b,
                float* __restrict__ h_out, bf16* __restrict__ qbf)
{
    __shared__ bf16 sIn[64 * 136];
    __shared__ bf16 sX[64 * 264];   // X, later reused as h (bf16)
    __shared__ bf16 sH[64 * 264];
    const int tid = threadIdx.x;
    const int wave = tid >> 6, lane = tid & 63;
    const int wm = wave >> 2, wn = wave & 3;
    const int m0 = blockIdx.x * 64;
    const int lr = lane & 15, l4 = (lane >> 4) << 2;

    // stage input [64,128] and hidden [64,256], f32 -> bf16
    for (int c = tid; c < 64 * 32; c += 512) {
        int r = c >> 5, cg = (c & 31) << 2;
        float4 f = *(const float4*)(in_f + (size_t)(m0 + r) * 128 + cg);
        bf16x4 o = { (bf16)f.x, (bf16)f.y, (bf16)f.z, (bf16)f.w };
        *(bf16x4*)&sIn[r * 136 + cg] = o;
    }
    for (int c = tid; c < 64 * 64; c += 512) {
        int r = c >> 6, cg = (c & 63) << 2;
        float4 f = *(const float4*)(hid_f + (size_t)(m0 + r) * 256 + cg);
        bf16x4 o = { (bf16)f.x, (bf16)f.y, (bf16)f.z, (bf16)f.w };
        *(bf16x4*)&sH[r * 264 + cg] = o;
    }
    __syncthreads();

    // phase 0: X = relu(in @ fc1w^T + b)  -> sX
    {
        f32x4 acc[2][4] = {};
        mm_f<2, 4, 128>(acc, sIn + wm * 32 * 136, 136, Wfc1 + (size_t)(wn * 64) * 128, 128, lane);
        #pragma unroll
        for (int i = 0; i < 2; ++i)
            #pragma unroll
            for (int j = 0; j < 4; ++j) {
                const int col = wn * 64 + j * 16 + lr;
                const float bv = fc1_b[col];
                #pragma unroll
                for (int r = 0; r < 4; ++r) {
                    const int row = wm * 32 + i * 16 + l4 + r;
                    sX[row * 264 + col] = (bf16)fmaxf(acc[i][j][r] + bv, 0.f);
                }
            }
    }
    __syncthreads();

    // phases 1-3: r, z, i_n, h_n
    f32x4 rg[2][4] = {}, zg[2][4] = {}, ni[2][4] = {}, nh[2][4] = {};
    mm_f<2, 4, 256>(rg, sX + wm * 32 * 264, 264, Wr + (size_t)(wn * 64) * 512, 512, lane);
    mm_f<2, 4, 256>(rg, sH + wm * 32 * 264, 264, Wr + (size_t)(wn * 64) * 512 + 256, 512, lane);
    mm_f<2, 4, 256>(zg, sX + wm * 32 * 264, 264, Wz + (size_t)(wn * 64) * 512, 512, lane);
    mm_f<2, 4, 256>(zg, sH + wm * 32 * 264, 264, Wz + (size_t)(wn * 64) * 512 + 256, 512, lane);
    mm_f<2, 4, 256>(ni, sX + wm * 32 * 264, 264, Wni + (size_t)(wn * 64) * 256, 256, lane);
    mm_f<2, 4, 256>(nh, sH + wm * 32 * 264, 264, Wnh + (size_t)(wn * 64) * 256, 256, lane);
    __syncthreads();   // all reads of sX done before h overwrites it

    // GRU epilogue: h -> h_out (f32) + sX (bf16)
    #pragma unroll
    for (int i = 0; i < 2; ++i)
        #pragma unroll
        for (int j = 0; j < 4; ++j) {
            const int col = wn * 64 + j * 16 + lr;
            const float br = b_ih[col] + b_hh[col];
            const float bz = b_ih[256 + col] + b_hh[256 + col];
            const float bin = b_ih[512 + col], bhn = b_hh[512 + col];
            #pragma unroll
            for (int r = 0; r < 4; ++r) {
                const int row = wm * 32 + i * 16 + l4 + r;
                const size_t grow = m0 + row;
                float rv = sigmf(rg[i][j][r] + br);
                float zv = sigmf(zg[i][j][r] + bz);
                float nn = tanh_fast((ni[i][j][r] + bin) + rv * (nh[i][j][r] + bhn));
                float hd = hid_f[grow * 256 + col];
                float h = (1.f - zv) * nn + zv * hd;
                h_out[grow * 256 + col] = h;
                sX[row * 264 + col] = (bf16)h;
            }
        }
    __syncthreads();

    // phase 4: q = h @ qw^T + q_b  -> qbf
    {
        f32x4 qa[2][1] = {};
        mm_f<2, 1, 256>(qa, sX + wm * 32 * 264, 264, Wq + (size_t)(wn * 16) * 256, 256, lane);
        #pragma unroll
        for (int i = 0; i < 2; ++i) {
            const int col = wn * 16 + lr;
            const float bv = q_b[col];
            #pragma unroll
            for (int r = 0; r < 4; ++r) {
                const size_t grow = m0 + wm * 32 + i * 16 + l4 + r;
                qbf[grow * 64 + col] = (bf16)(qa[i][0][r] + bv);
            }
        }
    }
}

// ---------------- msg K/V projection: one pass over msg (f32), N=320 ----------------
// 256 blocks x 512 threads; BM=64; wave grid 2x4, wave tile [32,80].
__global__ __launch_bounds__(512, 1)
void msgkv_k(const float* __restrict__ msg_f, const bf16* __restrict__ Wkv,
             bf16* __restrict__ msgk, bf16* __restrict__ msgv)
{
    __shared__ bf16 sA[64 * 72];
    const int tid = threadIdx.x;
    const int wave = tid >> 6, lane = tid & 63;
    const int wm = wave >> 2, wn = wave & 3;
    const int m0 = blockIdx.x * 64;
    const int lr = lane & 15, l4 = (lane >> 4) << 2;

    f32x4 acc[2][5] = {};
    for (int k0 = 0; k0 < 256; k0 += 64) {
        for (int c = tid; c < 64 * 16; c += 512) {
            int r = c >> 4, cg = (c & 15) << 2;
            float4 f = *(const float4*)(msg_f + (size_t)(m0 + r) * 256 + k0 + cg);
            bf16x4 o = { (bf16)f.x, (bf16)f.y, (bf16)f.z, (bf16)f.w };
            *(bf16x4*)&sA[r * 72 + cg] = o;
        }
        __syncthreads();
        mm_f<2, 5, 64>(acc, sA + wm * 32 * 72, 72, Wkv + (size_t)(wn * 80) * 256 + k0, 256, lane);
        __syncthreads();
    }
    #pragma unroll
    for (int i = 0; i < 2; ++i)
        #pragma unroll
        for (int j = 0; j < 5; ++j) {
            const int col = wn * 80 + j * 16 + lr;
            #pragma unroll
            for (int r = 0; r < 4; ++r) {
                const size_t row = m0 + wm * 32 + i * 16 + l4 + r;
                if (col < 64) msgk[row * 64 + col] = (bf16)acc[i][j][r];
                else          msgv[row * 256 + col - 64] = (bf16)acc[i][j][r];
            }
        }
}

// ---------------- attention + fc2a + fc2b, one block per batch ----------------
__global__ __launch_bounds__(512, 1)
void attnfc2_k(const float* __restrict__ h_out, const bf16* __restrict__ qbf,
               const bf16* __restrict__ msgk, const bf16* __restrict__ msgv,
               const int* __restrict__ topk, const float* __restrict__ v_bias,
               const bf16* __restrict__ Wf2a, const float* __restrict__ f2a_b,
               const bf16* __restrict__ Wf2b, const float* __restrict__ f2b_b,
               float* __restrict__ magg_out, float* __restrict__ q_out)
{
    __shared__ bf16 sH[64 * 264];
    __shared__ bf16 sV[64 * 264];   // V, later reused as y (fc2a output)
    __shared__ bf16 sM[64 * 264];
    __shared__ bf16 sQ[64 * 72];
    __shared__ bf16 sK[64 * 72];
    __shared__ int  sIdx[64 * 8];
    const int tid = threadIdx.x;
    const int wave = tid >> 6, lane = tid & 63;
    const int wm = wave >> 2, wn = wave & 3;
    const int b64 = blockIdx.x * 64;
    const int lr = lane & 15, l4 = (lane >> 4) << 2;

    // stage h (f32->bf16), q, K, V, topk
    for (int c = tid; c < 64 * 64; c += 512) {
        int r = c >> 6, cg = (c & 63) << 2;
        float4 f = *(const float4*)(h_out + (size_t)(b64 + r) * 256 + cg);
        bf16x4 o = { (bf16)f.x, (bf16)f.y, (bf16)f.z, (bf16)f.w };
        *(bf16x4*)&sH[r * 264 + cg] = o;
    }
    for (int c = tid; c < 64 * 8; c += 512) {
        int r = c >> 3, cg = (c & 7) << 3;
        *(bf16x8*)&sQ[r * 72 + cg] = *(const bf16x8*)(qbf + (size_t)(b64 + r) * 64 + cg);
        *(bf16x8*)&sK[r * 72 + cg] = *(const bf16x8*)(msgk + (size_t)(b64 + r) * 64 + cg);
    }
    for (int c = tid; c < 64 * 32; c += 512) {
        int r = c >> 5, cg = (c & 31) << 3;
        *(bf16x8*)&sV[r * 264 + cg] = *(const bf16x8*)(msgv + (size_t)(b64 + r) * 256 + cg);
    }
    for (int c = tid; c < 512; c += 512) sIdx[c] = topk[(size_t)b64 * 8 + c];
    __syncthreads();

    // attention: wave handles units wave*8 .. wave*8+7
    const int kk = lane >> 3, dg = lane & 7;
    #pragma unroll
    for (int uu = 0; uu < 8; ++uu) {
        const int u = wave * 8 + uu;
        const int rowk = sIdx[u * 8 + kk];
        // logit_kk = q[u] . K[rowk] / 8
        bf16x8 q8 = *(const bf16x8*)&sQ[u * 72 + dg * 8];
        bf16x8 k8 = *(const bf16x8*)&sK[rowk * 72 + dg * 8];
        float s = 0.f;
        #pragma unroll
        for (int t = 0; t < 8; ++t) s += (float)q8[t] * (float)k8[t];
        s += __shfl_xor(s, 1); s += __shfl_xor(s, 2); s += __shfl_xor(s, 4);
        float logit = s * 0.125f;
        // softmax over the 8 kk groups
        float mx = logit;
        mx = fmaxf(mx, __shfl_xor(mx, 8));
        mx = fmaxf(mx, __shfl_xor(mx, 16));
        mx = fmaxf(mx, __shfl_xor(mx, 32));
        float e = __expf(logit - mx);
        float den = e;
        den += __shfl_xor(den, 8); den += __shfl_xor(den, 16); den += __shfl_xor(den, 32);
        const float wv = e / den;
        // m_agg: lane -> 4 dims
        float a0 = 0.f, a1 = 0.f, a2 = 0.f, a3 = 0.f;
        #pragma unroll
        for (int k = 0; k < 8; ++k) {
            float wk = __shfl(wv, k * 8);
            int   rk = __shfl(rowk, k * 8);
            bf16x4 v = *(const bf16x4*)&sV[rk * 264 + lane * 4];
            a0 += wk * (float)v[0]; a1 += wk * (float)v[1];
            a2 += wk * (float)v[2]; a3 += wk * (float)v[3];
        }
        float4 vb = *(const float4*)(v_bias + lane * 4);
        a0 += vb.x; a1 += vb.y; a2 += vb.z; a3 += vb.w;
        float4 res = { a0, a1, a2, a3 };
        *(float4*)(magg_out + (size_t)(b64 + u) * 256 + lane * 4) = res;
        bf16x4 rb = { (bf16)a0, (bf16)a1, (bf16)a2, (bf16)a3 };
        *(bf16x4*)&sM[u * 264 + lane * 4] = rb;
    }
    __syncthreads();

    // fc2a: y = relu([h|m] @ f2aw^T + b) -> sV (reused)
    {
        f32x4 acc[2][4] = {};
        mm_f<2, 4, 256>(acc, sH + wm * 32 * 264, 264, Wf2a + (size_t)(wn * 64) * 512, 512, lane);
        mm_f<2, 4, 256>(acc, sM + wm * 32 * 264, 264, Wf2a + (size_t)(wn * 64) * 512 + 256, 512, lane);
        __syncthreads();   // all V reads done (already true) + before overwriting sV
        #pragma unroll
        for (int i = 0; i < 2; ++i)
            #pragma unroll
            for (int j = 0; j < 4; ++j) {
                const int col = wn * 64 + j * 16 + lr;
                const float bv = f2a_b[col];
                #pragma unroll
                for (int r = 0; r < 4; ++r) {
                    const int row = wm * 32 + i * 16 + l4 + r;
                    sV[row * 264 + col] = (bf16)fmaxf(acc[i][j][r] + bv, 0.f);
                }
            }
    }
    __syncthreads();

    // fc2b: q_out = y @ f2bw^T + b  (waves 0,1 only)
    if (wave < 2) {
        f32x4 acc[2][1] = {};
        mm_f<2, 1, 256>(acc, sV + wave * 32 * 264, 264, Wf2b, 256, lane);
        #pragma unroll
        for (int i = 0; i < 2; ++i) {
            const float bv = f2b_b[lr];
            #pragma unroll
            for (int r = 0; r < 4; ++r) {
                const size_t row = b64 + wave * 32 + i * 16 + l4 + r;
                q_out[row * 16 + lr] = acc[i][0][r] + bv;
            }
        }
    }
}

// ---------------- launch ----------------
extern "C" void kernel_launch(void* const* d_in, const int* in_sizes, int n_in,
                              void* d_out, int out_size, void* d_ws, size_t ws_size,
                              hipStream_t stream)
{
    const float* in_f   = (const float*)d_in[0];
    const float* hid_f  = (const float*)d_in[1];
    const float* msg_f  = (const float*)d_in[2];
    const int*   topk   = (const int*)d_in[3];
    const float* fc1w_f = (const float*)d_in[4];
    const float* fc1_b  = (const float*)d_in[5];
    const float* wih_f  = (const float*)d_in[6];
    const float* b_ih   = (const float*)d_in[7];
    const float* whh_f  = (const float*)d_in[8];
    const float* b_hh   = (const float*)d_in[9];
    const float* qw_f   = (const float*)d_in[10];
    const float* q_b    = (const float*)d_in[11];
    const float* kw_f   = (const float*)d_in[12];
    // d_in[13] = k_b: softmax-invariant, dropped.
    const float* vw_f   = (const float*)d_in[14];
    const float* v_b    = (const float*)d_in[15];
    const float* f2aw_f = (const float*)d_in[16];
    const float* f2a_b  = (const float*)d_in[17];
    const float* f2bw_f = (const float*)d_in[18];
    const float* f2b_b  = (const float*)d_in[19];

    bf16* ws   = (bf16*)d_ws;
    bf16* Wr   = ws + OFF_WR;
    bf16* Wz   = ws + OFF_WZ;
    bf16* Wni  = ws + OFF_WNI;
    bf16* Wnh  = ws + OFF_WNH;
    bf16* fc1w = ws + OFF_FC1W;
    bf16* qw   = ws + OFF_QW;
    bf16* Wkv  = ws + OFF_WKV;
    bf16* f2aw = ws + OFF_F2AW;
    bf16* f2bw = ws + OFF_F2BW;
    bf16* qbf  = ws + OFF_QB;
    bf16* msgk = ws + OFF_MSGK;
    bf16* msgv = ws + OFF_MSGV;

    float* q_out    = (float*)d_out;                 // [16384,16]
    float* h_out    = q_out + (size_t)ROWS * 16;     // [16384,256]
    float* magg_out = h_out + (size_t)ROWS * 256;    // [16384,256]

    // 1) convert weights to bf16 (with concat layouts)
    CvtArgs ca{};
    int s = 0;
    auto add = [&](const float* src, bf16* dst, int n, int cw, int ld, int off) {
        ca.seg[s].src = src; ca.seg[s].dst = dst; ca.seg[s].n = n;
        ca.seg[s].cw = cw; ca.seg[s].ld = ld; ca.seg[s].off = off; ++s;
    };
    add(fc1w_f, fc1w, 32768, 32768, 0, 0);
    add(wih_f,          Wr, 65536, 256, 512, 0);     // Wih rows 0..255   -> Wr[:,0:256]
    add(whh_f,          Wr, 65536, 256, 512, 256);   // Whh rows 0..255   -> Wr[:,256:512]
    add(wih_f +  65536, Wz, 65536, 256, 512, 0);     // Wih rows 256..511 -> Wz[:,0:256]
    add(whh_f +  65536, Wz, 65536, 256, 512, 256);
    add(wih_f + 131072, Wni, 65536, 65536, 0, 0);    // n-gate rows 512..767
    add(whh_f + 131072, Wnh, 65536, 65536, 0, 0);
    add(qw_f, qw, 16384, 16384, 0, 0);
    add(kw_f, Wkv, 16384, 16384, 0, 0);              // kw -> Wkv rows 0..63
    add(vw_f, Wkv + 16384, 65536, 65536, 0, 0);      // vw -> Wkv rows 64..319
    add(f2aw_f, f2aw, 131072, 131072, 0, 0);
    add(f2bw_f, f2bw, 4096, 4096, 0, 0);
    ca.count = s;
    convert_k<<<256, 256, 0, stream>>>(ca);

    // 2) msg K/V projections (single pass over msg)
    msgkv_k<<<256, 512, 0, stream>>>(msg_f, Wkv, msgk, msgv);

    // 3) fused fc1 + GRU + q projection
    gru_mega_k<<<256, 512, 0, stream>>>(in_f, hid_f, fc1w, fc1_b,
                                        Wr, Wz, Wni, Wnh, b_ih, b_hh,
                                        qw, q_b, h_out, qbf);

    // 4) attention + fc2a + fc2b (one block per batch)
    attnfc2_k<<<256, 512, 0, stream>>>(h_out, qbf, msgk, msgv, topk, v_b,
                                       f2aw, f2a_b, f2bw, f2b_b, magg_out, q_out);
}

// Round 3
// 75.801 us; speedup vs baseline: 1.9755x; 1.7032x over previous
//
#include <hip/hip_runtime.h>

typedef __bf16 bf16;
typedef __attribute__((ext_vector_type(8))) __bf16 bf16x8;
typedef __attribute__((ext_vector_type(4))) __bf16 bf16x4;
typedef __attribute__((ext_vector_type(4))) float f32x4;

static constexpr int ROWS = 16384;   // BS*N_AGENTS

// ---------------- workspace layout (bf16 elements) ----------------
// Swizzled weights: element (n,k) of an [N,K] matrix lives at
//   ((n/16)*(K/32) + k/32)*512 + lane*8 + (k&7),  lane = (n&15) | (((k>>3)&3)<<4)
// so a wave's MFMA B-fragment (n16, k32) is one contiguous 1 KB block.
static constexpr size_t OFF_WFC1 = 0;        // [256,128]
static constexpr size_t OFF_WRX  = 32768;    // [256,256] Wih rows 0-255
static constexpr size_t OFF_WZX  = 98304;    // [256,256] Wih rows 256-511
static constexpr size_t OFF_WNI  = 163840;   // [256,256] Wih rows 512-767
static constexpr size_t OFF_WRH  = 229376;   // [256,256] Whh rows 0-255
static constexpr size_t OFF_WZH  = 294912;   // [256,256] Whh rows 256-511
static constexpr size_t OFF_WNH  = 360448;   // [256,256] Whh rows 512-767
static constexpr size_t OFF_WQ   = 425984;   // [64,256]
static constexpr size_t OFF_WKV  = 442368;   // [320,256]: kw n16 0-3, vw n16 4-19
static constexpr size_t OFF_F2AH = 524288;   // [256,256] f2aw cols 0-255
static constexpr size_t OFF_F2AM = 589824;   // [256,256] f2aw cols 256-511
static constexpr size_t OFF_WF2B = 655360;   // [16,256]
static constexpr size_t OFF_HNEW = 659456;   // [16384,256] h (bf16)
static constexpr size_t OFF_MSGK = 4853760;  // [16384,64]
static constexpr size_t OFF_MSGV = 5902336;  // [16384,256]

// ---------------- weight swizzle (f32 row-major -> bf16 fragment-major) ----------------
struct SwzSeg { const float* src; bf16* dst; int items; int k8s; int k32; int ld; };
struct SwzArgs { SwzSeg seg[13]; int count; };

__global__ __launch_bounds__(256) void swz_k(SwzArgs a) {
    const int tid = blockIdx.x * 256 + threadIdx.x;
    const int stride = gridDim.x * 256;
    for (int s = 0; s < a.count; ++s) {
        const float* __restrict__ src = a.seg[s].src;
        bf16* __restrict__ dst = a.seg[s].dst;
        const int items = a.seg[s].items, k8s = a.seg[s].k8s;
        const int k32c = a.seg[s].k32, ld = a.seg[s].ld;
        for (int i = tid; i < items; i += stride) {
            const int n = i >> k8s, kb = i & ((1 << k8s) - 1);
            const int k0 = kb << 3;
            const int lane = (n & 15) | ((kb & 3) << 4);
            const size_t off = ((size_t)((n >> 4) * k32c + (kb >> 2)) * 64 + lane) * 8;
            const float* p = src + (size_t)n * ld + k0;
            float4 f0 = *(const float4*)p;
            float4 f1 = *(const float4*)(p + 4);
            bf16x8 o = { (bf16)f0.x, (bf16)f0.y, (bf16)f0.z, (bf16)f0.w,
                         (bf16)f1.x, (bf16)f1.y, (bf16)f1.z, (bf16)f1.w };
            *(bf16x8*)(dst + off) = o;
        }
    }
}

// ---------------- MFMA helper: acc += A_lds @ Wswz^T, full K = K32*32 ----------------
template<int FM, int FN, int K32>
__device__ __forceinline__ void mm_swz(f32x4 (&acc)[FM][FN],
    const bf16* __restrict__ sA, int lda,
    const bf16* __restrict__ W /* pre-offset to wave's n16 base */, int lane)
{
    const int lr = lane & 15, lk = (lane >> 4) << 3;
    #pragma unroll
    for (int k32 = 0; k32 < K32; ++k32) {
        bf16x8 a[FM], b[FN];
        #pragma unroll
        for (int i = 0; i < FM; ++i)
            a[i] = *(const bf16x8*)&sA[(i * 16 + lr) * lda + k32 * 32 + lk];
        #pragma unroll
        for (int j = 0; j < FN; ++j)
            b[j] = *(const bf16x8*)(W + ((size_t)(j * K32 + k32) * 64 + lane) * 8);
        #pragma unroll
        for (int i = 0; i < FM; ++i)
            #pragma unroll
            for (int j = 0; j < FN; ++j)
                acc[i][j] = __builtin_amdgcn_mfma_f32_16x16x32_bf16(a[i], b[j], acc[i][j], 0, 0, 0);
    }
}

__device__ __forceinline__ float sigmf(float x) { return 1.f / (1.f + __expf(-x)); }
__device__ __forceinline__ float tanh_fast(float x) {
    x = fminf(fmaxf(x, -15.f), 15.f);
    float e2 = __expf(2.f * x);
    return (e2 - 1.f) / (e2 + 1.f);
}

// ---------------- GRU kernel: fc1 + all gates + h, BM=32, 8 waves ----------------
__global__ __launch_bounds__(512)
void gru_k(const float* __restrict__ in_f, const float* __restrict__ hid_f,
           const bf16* __restrict__ Wfc1, const float* __restrict__ fc1_b,
           const bf16* __restrict__ WrX, const bf16* __restrict__ WrH,
           const bf16* __restrict__ WzX, const bf16* __restrict__ WzH,
           const bf16* __restrict__ Wni, const bf16* __restrict__ Wnh,
           const float* __restrict__ b_ih, const float* __restrict__ b_hh,
           float* __restrict__ h_out, bf16* __restrict__ hnew)
{
    __shared__ bf16 sIn[32 * 136];
    __shared__ bf16 sX[32 * 264];
    __shared__ bf16 sH[32 * 264];
    const int tid = threadIdx.x;
    const int wave = tid >> 6, lane = tid & 63;
    const int m0 = blockIdx.x * 32;
    const int lr = lane & 15, l4 = (lane >> 4) << 2, lk = (lane >> 4) << 3;

    // stage in [32,128], hidden [32,256] (f32 -> bf16)
    for (int c = tid; c < 1024; c += 512) {
        int r = c >> 5, cg = (c & 31) << 2;
        float4 f = *(const float4*)(in_f + (size_t)(m0 + r) * 128 + cg);
        bf16x4 o = { (bf16)f.x, (bf16)f.y, (bf16)f.z, (bf16)f.w };
        *(bf16x4*)&sIn[r * 136 + cg] = o;
    }
    for (int c = tid; c < 2048; c += 512) {
        int r = c >> 6, cg = (c & 63) << 2;
        float4 f = *(const float4*)(hid_f + (size_t)(m0 + r) * 256 + cg);
        bf16x4 o = { (bf16)f.x, (bf16)f.y, (bf16)f.z, (bf16)f.w };
        *(bf16x4*)&sH[r * 264 + cg] = o;
    }
    __syncthreads();

    // fc1: X = relu(in @ fc1w^T + b) -> sX ; wave covers cols [wave*32, wave*32+32)
    {
        f32x4 acc[2][2] = {};
        mm_swz<2, 2, 4>(acc, sIn, 136, Wfc1 + (size_t)wave * 2 * 4 * 512, lane);
        #pragma unroll
        for (int i = 0; i < 2; ++i)
            #pragma unroll
            for (int j = 0; j < 2; ++j) {
                const int col = wave * 32 + j * 16 + lr;
                const float bv = fc1_b[col];
                #pragma unroll
                for (int rr = 0; rr < 4; ++rr) {
                    const int row = i * 16 + l4 + rr;
                    sX[row * 264 + col] = (bf16)fmaxf(acc[i][j][rr] + bv, 0.f);
                }
            }
    }
    __syncthreads();

    // gates: r, z, i_n, h_n (each [32,32] per wave; 64 acc VGPRs total)
    f32x4 rg[2][2] = {}, zg[2][2] = {}, ng[2][2] = {}, hg[2][2] = {};
    const size_t nb = (size_t)wave * 2 * 8 * 512;   // n16 base offset
    const bf16 *pRX = WrX + nb, *pZX = WzX + nb, *pNI = Wni + nb;
    const bf16 *pRH = WrH + nb, *pZH = WzH + nb, *pNH = Wnh + nb;
    #pragma unroll
    for (int k32 = 0; k32 < 8; ++k32) {
        const size_t bo = (size_t)k32 * 512 + lane * 8;
        bf16x8 ax[2], ah[2];
        #pragma unroll
        for (int i = 0; i < 2; ++i) {
            ax[i] = *(const bf16x8*)&sX[(i * 16 + lr) * 264 + k32 * 32 + lk];
            ah[i] = *(const bf16x8*)&sH[(i * 16 + lr) * 264 + k32 * 32 + lk];
        }
        bf16x8 brx[2], bzx[2], bni[2], brh[2], bzh[2], bnh[2];
        #pragma unroll
        for (int j = 0; j < 2; ++j) {
            brx[j] = *(const bf16x8*)(pRX + (size_t)j * 4096 + bo);
            bzx[j] = *(const bf16x8*)(pZX + (size_t)j * 4096 + bo);
            bni[j] = *(const bf16x8*)(pNI + (size_t)j * 4096 + bo);
            brh[j] = *(const bf16x8*)(pRH + (size_t)j * 4096 + bo);
            bzh[j] = *(const bf16x8*)(pZH + (size_t)j * 4096 + bo);
            bnh[j] = *(const bf16x8*)(pNH + (size_t)j * 4096 + bo);
        }
        #pragma unroll
        for (int i = 0; i < 2; ++i)
            #pragma unroll
            for (int j = 0; j < 2; ++j) {
                rg[i][j] = __builtin_amdgcn_mfma_f32_16x16x32_bf16(ax[i], brx[j], rg[i][j], 0, 0, 0);
                zg[i][j] = __builtin_amdgcn_mfma_f32_16x16x32_bf16(ax[i], bzx[j], zg[i][j], 0, 0, 0);
                ng[i][j] = __builtin_amdgcn_mfma_f32_16x16x32_bf16(ax[i], bni[j], ng[i][j], 0, 0, 0);
                rg[i][j] = __builtin_amdgcn_mfma_f32_16x16x32_bf16(ah[i], brh[j], rg[i][j], 0, 0, 0);
                zg[i][j] = __builtin_amdgcn_mfma_f32_16x16x32_bf16(ah[i], bzh[j], zg[i][j], 0, 0, 0);
                hg[i][j] = __builtin_amdgcn_mfma_f32_16x16x32_bf16(ah[i], bnh[j], hg[i][j], 0, 0, 0);
            }
    }

    // GRU epilogue
    #pragma unroll
    for (int i = 0; i < 2; ++i)
        #pragma unroll
        for (int j = 0; j < 2; ++j) {
            const int col = wave * 32 + j * 16 + lr;
            const float br = b_ih[col] + b_hh[col];
            const float bz = b_ih[256 + col] + b_hh[256 + col];
            const float bi = b_ih[512 + col], bh = b_hh[512 + col];
            #pragma unroll
            for (int rr = 0; rr < 4; ++rr) {
                const int row = i * 16 + l4 + rr;
                const size_t grow = m0 + row;
                float rv = sigmf(rg[i][j][rr] + br);
                float zv = sigmf(zg[i][j][rr] + bz);
                float nn = tanh_fast((ng[i][j][rr] + bi) + rv * (hg[i][j][rr] + bh));
                float hd = (float)sH[row * 264 + col];
                float h = (1.f - zv) * nn + zv * hd;
                h_out[grow * 256 + col] = h;
                hnew[grow * 256 + col] = (bf16)h;
            }
        }
}

// ---------------- msg K/V projection: BM=64, N=320 ----------------
__global__ __launch_bounds__(512)
void msgkv_k(const float* __restrict__ msg_f, const bf16* __restrict__ Wkv,
             bf16* __restrict__ msgk, bf16* __restrict__ msgv)
{
    __shared__ bf16 sA[64 * 264];
    const int tid = threadIdx.x;
    const int wave = tid >> 6, lane = tid & 63;
    const int wm = wave >> 2, wn = wave & 3;
    const int m0 = blockIdx.x * 64;
    const int lr = lane & 15, l4 = (lane >> 4) << 2;

    for (int c = tid; c < 4096; c += 512) {
        int r = c >> 6, cg = (c & 63) << 2;
        float4 f = *(const float4*)(msg_f + (size_t)(m0 + r) * 256 + cg);
        bf16x4 o = { (bf16)f.x, (bf16)f.y, (bf16)f.z, (bf16)f.w };
        *(bf16x4*)&sA[r * 264 + cg] = o;
    }
    __syncthreads();

    f32x4 acc[2][5] = {};
    mm_swz<2, 5, 8>(acc, sA + wm * 32 * 264, 264, Wkv + (size_t)(wn * 5) * 8 * 512, lane);

    #pragma unroll
    for (int i = 0; i < 2; ++i)
        #pragma unroll
        for (int j = 0; j < 5; ++j) {
            const int col = wn * 80 + j * 16 + lr;
            #pragma unroll
            for (int rr = 0; rr < 4; ++rr) {
                const size_t row = m0 + wm * 32 + i * 16 + l4 + rr;
                if (col < 64) msgk[row * 64 + col] = (bf16)acc[i][j][rr];
                else          msgv[row * 256 + col - 64] = (bf16)acc[i][j][rr];
            }
        }
}

// ---------------- q-proj + attention + fc2a + fc2b, one block per batch ----------------
__global__ __launch_bounds__(512)
void attnfc2_k(const bf16* __restrict__ hnew, const bf16* __restrict__ msgk,
               const bf16* __restrict__ msgv, const int* __restrict__ topk,
               const bf16* __restrict__ Wq, const float* __restrict__ q_b,
               const float* __restrict__ v_bias,
               const bf16* __restrict__ f2aH, const bf16* __restrict__ f2aM,
               const float* __restrict__ f2a_b,
               const bf16* __restrict__ Wf2b, const float* __restrict__ f2b_b,
               float* __restrict__ magg_out, float* __restrict__ q_out)
{
    __shared__ bf16 sH[64 * 264];
    __shared__ bf16 sV[64 * 264];   // V, later reused as y (fc2a output)
    __shared__ bf16 sM[64 * 264];
    __shared__ bf16 sQ[64 * 72];
    __shared__ bf16 sK[64 * 72];
    __shared__ int  sIdx[512];
    const int tid = threadIdx.x;
    const int wave = tid >> 6, lane = tid & 63;
    const int wm = wave >> 2, wn = wave & 3;
    const int b64 = blockIdx.x * 64;
    const int lr = lane & 15, l4 = (lane >> 4) << 2;

    // stage h (bf16 direct), K, V, topk
    for (int c = tid; c < 2048; c += 512) {
        int r = c >> 5, cg = (c & 31) << 3;
        *(bf16x8*)&sH[r * 264 + cg] = *(const bf16x8*)(hnew + (size_t)(b64 + r) * 256 + cg);
        *(bf16x8*)&sV[r * 264 + cg] = *(const bf16x8*)(msgv + (size_t)(b64 + r) * 256 + cg);
    }
    for (int c = tid; c < 512; c += 512) {
        int r = c >> 3, cg = (c & 7) << 3;
        *(bf16x8*)&sK[r * 72 + cg] = *(const bf16x8*)(msgk + (size_t)(b64 + r) * 64 + cg);
        sIdx[c] = topk[(size_t)b64 * 8 + c];
    }
    __syncthreads();

    // q = h @ qw^T + q_b -> sQ  (wave tile [32,16])
    {
        f32x4 qa[2][1] = {};
        mm_swz<2, 1, 8>(qa, sH + wm * 32 * 264, 264, Wq + (size_t)wn * 8 * 512, lane);
        #pragma unroll
        for (int i = 0; i < 2; ++i) {
            const int col = wn * 16 + lr;
            const float bv = q_b[col];
            #pragma unroll
            for (int rr = 0; rr < 4; ++rr) {
                const int row = wm * 32 + i * 16 + l4 + rr;
                sQ[row * 72 + col] = (bf16)(qa[i][0][rr] + bv);
            }
        }
    }
    __syncthreads();

    // attention: wave handles units wave*8 .. wave*8+7
    const int kk = lane >> 3, dg = lane & 7;
    #pragma unroll
    for (int uu = 0; uu < 8; ++uu) {
        const int u = wave * 8 + uu;
        const int rowk = sIdx[u * 8 + kk];
        bf16x8 q8 = *(const bf16x8*)&sQ[u * 72 + dg * 8];
        bf16x8 k8 = *(const bf16x8*)&sK[rowk * 72 + dg * 8];
        float s = 0.f;
        #pragma unroll
        for (int t = 0; t < 8; ++t) s += (float)q8[t] * (float)k8[t];
        s += __shfl_xor(s, 1); s += __shfl_xor(s, 2); s += __shfl_xor(s, 4);
        float logit = s * 0.125f;
        float mx = logit;
        mx = fmaxf(mx, __shfl_xor(mx, 8));
        mx = fmaxf(mx, __shfl_xor(mx, 16));
        mx = fmaxf(mx, __shfl_xor(mx, 32));
        float e = __expf(logit - mx);
        float den = e;
        den += __shfl_xor(den, 8); den += __shfl_xor(den, 16); den += __shfl_xor(den, 32);
        const float wv = e / den;
        float a0 = 0.f, a1 = 0.f, a2 = 0.f, a3 = 0.f;
        #pragma unroll
        for (int k = 0; k < 8; ++k) {
            float wk = __shfl(wv, k * 8);
            int   rk = __shfl(rowk, k * 8);
            bf16x4 v = *(const bf16x4*)&sV[rk * 264 + lane * 4];
            a0 += wk * (float)v[0]; a1 += wk * (float)v[1];
            a2 += wk * (float)v[2]; a3 += wk * (float)v[3];
        }
        float4 vb = *(const float4*)(v_bias + lane * 4);
        a0 += vb.x; a1 += vb.y; a2 += vb.z; a3 += vb.w;
        float4 res = { a0, a1, a2, a3 };
        *(float4*)(magg_out + (size_t)(b64 + u) * 256 + lane * 4) = res;
        bf16x4 rb = { (bf16)a0, (bf16)a1, (bf16)a2, (bf16)a3 };
        *(bf16x4*)&sM[u * 264 + lane * 4] = rb;
    }
    __syncthreads();

    // fc2a: y = relu([h|m] @ f2aw^T + b) -> sV (reused)
    {
        f32x4 acc[2][4] = {};
        mm_swz<2, 4, 8>(acc, sH + wm * 32 * 264, 264, f2aH + (size_t)(wn * 4) * 8 * 512, lane);
        mm_swz<2, 4, 8>(acc, sM + wm * 32 * 264, 264, f2aM + (size_t)(wn * 4) * 8 * 512, lane);
        __syncthreads();   // all sV (V) reads complete before overwrite
        #pragma unroll
        for (int i = 0; i < 2; ++i)
            #pragma unroll
            for (int j = 0; j < 4; ++j) {
                const int col = wn * 64 + j * 16 + lr;
                const float bv = f2a_b[col];
                #pragma unroll
                for (int rr = 0; rr < 4; ++rr) {
                    const int row = wm * 32 + i * 16 + l4 + rr;
                    sV[row * 264 + col] = (bf16)fmaxf(acc[i][j][rr] + bv, 0.f);
                }
            }
    }
    __syncthreads();

    // fc2b: q_out = y @ f2bw^T + b  (waves 0-3, [16,16] tiles)
    if (wave < 4) {
        f32x4 acc[1][1] = {};
        mm_swz<1, 1, 8>(acc, sV + wave * 16 * 264, 264, Wf2b, lane);
        const float bv = f2b_b[lr];
        #pragma unroll
        for (int rr = 0; rr < 4; ++rr) {
            const size_t row = b64 + wave * 16 + l4 + rr;
            q_out[row * 16 + lr] = acc[0][0][rr] + bv;
        }
    }
}

// ---------------- launch ----------------
extern "C" void kernel_launch(void* const* d_in, const int* in_sizes, int n_in,
                              void* d_out, int out_size, void* d_ws, size_t ws_size,
                              hipStream_t stream)
{
    const float* in_f   = (const float*)d_in[0];
    const float* hid_f  = (const float*)d_in[1];
    const float* msg_f  = (const float*)d_in[2];
    const int*   topk   = (const int*)d_in[3];
    const float* fc1w_f = (const float*)d_in[4];
    const float* fc1_b  = (const float*)d_in[5];
    const float* wih_f  = (const float*)d_in[6];
    const float* b_ih   = (const float*)d_in[7];
    const float* whh_f  = (const float*)d_in[8];
    const float* b_hh   = (const float*)d_in[9];
    const float* qw_f   = (const float*)d_in[10];
    const float* q_b    = (const float*)d_in[11];
    const float* kw_f   = (const float*)d_in[12];
    // d_in[13] = k_b: softmax-invariant, dropped.
    const float* vw_f   = (const float*)d_in[14];
    const float* v_b    = (const float*)d_in[15];
    const float* f2aw_f = (const float*)d_in[16];
    const float* f2a_b  = (const float*)d_in[17];
    const float* f2bw_f = (const float*)d_in[18];
    const float* f2b_b  = (const float*)d_in[19];

    bf16* ws = (bf16*)d_ws;
    bf16* Wfc1 = ws + OFF_WFC1;
    bf16* WrX  = ws + OFF_WRX;
    bf16* WzX  = ws + OFF_WZX;
    bf16* Wni  = ws + OFF_WNI;
    bf16* WrH  = ws + OFF_WRH;
    bf16* WzH  = ws + OFF_WZH;
    bf16* Wnh  = ws + OFF_WNH;
    bf16* Wq   = ws + OFF_WQ;
    bf16* Wkv  = ws + OFF_WKV;
    bf16* f2aH = ws + OFF_F2AH;
    bf16* f2aM = ws + OFF_F2AM;
    bf16* Wf2b = ws + OFF_WF2B;
    bf16* hnew = ws + OFF_HNEW;
    bf16* msgk = ws + OFF_MSGK;
    bf16* msgv = ws + OFF_MSGV;

    float* q_out    = (float*)d_out;                 // [16384,16]
    float* h_out    = q_out + (size_t)ROWS * 16;     // [16384,256]
    float* magg_out = h_out + (size_t)ROWS * 256;    // [16384,256]

    // 1) swizzle weights to fragment-major bf16
    SwzArgs sa{};
    int s = 0;
    auto add = [&](const float* src, bf16* dst, int N, int K, int ld) {
        sa.seg[s].src = src; sa.seg[s].dst = dst;
        sa.seg[s].items = N * (K >> 3);
        sa.seg[s].k8s = (K == 128) ? 4 : 5;
        sa.seg[s].k32 = K >> 5;
        sa.seg[s].ld = ld; ++s;
    };
    add(fc1w_f,          Wfc1, 256, 128, 128);
    add(wih_f,           WrX,  256, 256, 256);
    add(wih_f +  65536,  WzX,  256, 256, 256);
    add(wih_f + 131072,  Wni,  256, 256, 256);
    add(whh_f,           WrH,  256, 256, 256);
    add(whh_f +  65536,  WzH,  256, 256, 256);
    add(whh_f + 131072,  Wnh,  256, 256, 256);
    add(qw_f,            Wq,    64, 256, 256);
    add(kw_f,            Wkv,   64, 256, 256);
    add(vw_f,            Wkv + 16384, 256, 256, 256);
    add(f2aw_f,          f2aH, 256, 256, 512);
    add(f2aw_f + 256,    f2aM, 256, 256, 512);
    add(f2bw_f,          Wf2b,  16, 256, 256);
    sa.count = s;
    swz_k<<<256, 256, 0, stream>>>(sa);

    // 2) fused fc1 + GRU
    gru_k<<<512, 512, 0, stream>>>(in_f, hid_f, Wfc1, fc1_b,
                                   WrX, WrH, WzX, WzH, Wni, Wnh,
                                   b_ih, b_hh, h_out, hnew);

    // 3) msg K/V projections
    msgkv_k<<<256, 512, 0, stream>>>(msg_f, Wkv, msgk, msgv);

    // 4) q-proj + attention + fc2a + fc2b
    attnfc2_k<<<256, 512, 0, stream>>>(hnew, msgk, msgv, topk,
                                       Wq, q_b, v_b, f2aH, f2aM, f2a_b,
                                       Wf2b, f2b_b, magg_out, q_out);
}